// Round 1
// baseline (8246.320 us; speedup 1.0000x reference)
//
#include <hip/hip_runtime.h>
#include <math.h>

#define BATCH 128
#define TSTEPS 4096
#define INDIM 13
#define XT 64   // steps per x/out LDS tile

// ============================================================================
// 2-barrier schedule. Per iteration ts (ts = -1 bootstraps LSTM^0):
//   region B: CfC0^ts (lanes 0..139, K4) || x-tile refill / out flush /
//             x_{ts+1} copy into zLa + z0[par^1]
//   barrier
//   region C: per-wave, wave-synchronous (lgkmcnt fences, no barriers):
//             CfC1^ts (K2, lanes l<46 of EVERY wave, redundant)
//          -> CfC2^ts (K2, lanes l in [46,58) of EVERY wave, redundant)
//          -> LSTM^{ts+1} (all lanes, K4 quad split, unchanged math)
//   barrier
// Cross-wave values (h0,h1,h2,o0,x) cross a barrier; o1,o2 stay wave-local.
//
// LDS layout (floats):
//   z0  @0    : 2 x 48  [x_t | h0_lstm^t]        parity t&1
//   zLa @96   : 48      [x_{t+1} | o0^t]         (LSTM k<2 source)
//   z1  @144  : 2 x 64  [o0^t | h1^t | pad]      parity t&1
//   z2  @272  : 4w x 2p x 32 [o1^t | h2^t | pad] per-wave + parity
//   zLb @528  : 4w x 48 [o1^t | o2^t | pad]      per-wave (LSTM k>=2 source)
//   xt0 @720 (832) | xt1 @1552 (832)             x tiles, double-buffered
//   ot0 @2384 (384) | ot1 @2768 (384)            out tiles, double-buffered
// ============================================================================

__device__ __forceinline__ float fsig(float x) {
    return __builtin_amdgcn_rcpf(1.f + __expf(-x));
}
__device__ __forceinline__ float ftanh(float x) {
    float s = fsig(x + x);
    return s + s - 1.f;
}
__device__ __forceinline__ float fsoftplus(float x) {
    return (x > 15.f) ? x : __logf(1.f + __expf(x));
}

// quad exchanges via DPP (VALU latency, no LDS pipe)
__device__ __forceinline__ float qxor1(float v) {   // quad_perm [1,0,3,2]
    return __int_as_float(__builtin_amdgcn_update_dpp(
        0, __float_as_int(v), 0xB1, 0xF, 0xF, true));
}
__device__ __forceinline__ float qxor2(float v) {   // quad_perm [2,3,0,1]
    return __int_as_float(__builtin_amdgcn_update_dpp(
        0, __float_as_int(v), 0x4E, 0xF, 0xF, true));
}
#define BFLY4(a) { a += qxor1(a); a += qxor2(a); }

#define FMA4(acc, W, q, zv) { acc += zv.x * W##_##q##_0; acc += zv.y * W##_##q##_1; \
                              acc += zv.z * W##_##q##_2; acc += zv.w * W##_##q##_3; }

// intra-wave producer->consumer fence (same-wave DS ordering + compile fence)
#define LDS_FENCE() { asm volatile("s_waitcnt lgkmcnt(0)" ::: "memory"); \
                      __builtin_amdgcn_sched_barrier(0); }

__global__ __launch_bounds__(256, 1)
void rnn_kernel(const float* __restrict__ x,
                const float* __restrict__ lstm_wi, const float* __restrict__ lstm_wh,
                const float* __restrict__ lstm_b,
                const float* __restrict__ c0w1, const float* __restrict__ c0w2,
                const float* __restrict__ c0wa, const float* __restrict__ c0wb,
                const float* __restrict__ c0b1, const float* __restrict__ c0b2,
                const float* __restrict__ c0ba, const float* __restrict__ c0bb,
                const float* __restrict__ c1w1, const float* __restrict__ c1w2,
                const float* __restrict__ c1wa, const float* __restrict__ c1wb,
                const float* __restrict__ c1b1, const float* __restrict__ c1b2,
                const float* __restrict__ c1ba, const float* __restrict__ c1bb,
                const float* __restrict__ c2w1, const float* __restrict__ c2w2,
                const float* __restrict__ c2wa, const float* __restrict__ c2wb,
                const float* __restrict__ c2b1, const float* __restrict__ c2b2,
                const float* __restrict__ c2ba, const float* __restrict__ c2bb,
                float* __restrict__ out)
{
    const int bb = blockIdx.x;
    const int t  = threadIdx.x;     // 0..255
    const int k  = t & 3;           // LSTM K-chunk slot within the quad
    const int u  = t >> 2;          // LSTM unit index 0..63
    const int l  = t & 63;          // lane within wave
    const int w  = t >> 6;          // wave index 0..3
    const int cu1 = l >> 1, h1 = l & 1;     // CfC1 role (valid for l < 46)
    const int c2i = l - 46;                 // CfC2 role (valid for 0 <= c2i < 12)
    const int cu2 = c2i >> 1, h2 = c2i & 1;

    __shared__ __align__(16) float smem[3152];
    float* z0  = smem;           // 2 x 48
    float* zLa = smem + 96;      // 48
    float* z1  = smem + 144;     // 2 x 64
    float* z2  = smem + 272;     // 4 x 2 x 32
    float* zLb = smem + 528;     // 4 x 48
    float* xt0 = smem + 720;
    float* xt1 = smem + 1552;
    float* ot0 = smem + 2384;
    float* ot1 = smem + 2768;

    const long xbase = (long)bb * TSTEPS * INDIM;
    const long obase = (long)bb * TSTEPS * 6;

    // ---- LSTM weights: lane (u,k) holds cols [24k,24k+24) of all 4 gate rows
    auto lwf = [&](int A, int c) -> float {
        int r = A * 64 + u;
        return (c < 13) ? lstm_wi[r * 13 + c]
             : (c < 77) ? lstm_wh[r * 64 + (c - 13)] : 0.f;
    };
#define DEF_WL(A,q) \
    float wl##A##_##q##_0 = lwf(A, 24*k + 4*q + 0); \
    float wl##A##_##q##_1 = lwf(A, 24*k + 4*q + 1); \
    float wl##A##_##q##_2 = lwf(A, 24*k + 4*q + 2); \
    float wl##A##_##q##_3 = lwf(A, 24*k + 4*q + 3);
    DEF_WL(0,0) DEF_WL(0,1) DEF_WL(0,2) DEF_WL(0,3) DEF_WL(0,4) DEF_WL(0,5)
    DEF_WL(1,0) DEF_WL(1,1) DEF_WL(1,2) DEF_WL(1,3) DEF_WL(1,4) DEF_WL(1,5)
    DEF_WL(2,0) DEF_WL(2,1) DEF_WL(2,2) DEF_WL(2,3) DEF_WL(2,4) DEF_WL(2,5)
    DEF_WL(3,0) DEF_WL(3,1) DEF_WL(3,2) DEF_WL(3,3) DEF_WL(3,4) DEF_WL(3,5)
#undef DEF_WL
    const float bL0 = lstm_b[u];
    const float bL1 = lstm_b[64 + u];
    const float bL2 = lstm_b[128 + u];
    const float bL3 = lstm_b[192 + u];

    // ---- CfC0 weights: lanes t<140 (u<35), K4, 12-col chunk at 12k (exact)
    const float *P0 = c0w1, *P1 = c0w2, *P2 = c0wa, *P3 = c0wb;
    auto c0f = [&](const float* Wp, int c) -> float {
        return (t < 140) ? Wp[u * 48 + 12 * k + c] : 0.f;
    };
#define DEF_WA(A,q) \
    float wa##A##_##q##_0 = c0f(P##A, 4*q + 0); \
    float wa##A##_##q##_1 = c0f(P##A, 4*q + 1); \
    float wa##A##_##q##_2 = c0f(P##A, 4*q + 2); \
    float wa##A##_##q##_3 = c0f(P##A, 4*q + 3);
    DEF_WA(0,0) DEF_WA(0,1) DEF_WA(0,2)
    DEF_WA(1,0) DEF_WA(1,1) DEF_WA(1,2)
    DEF_WA(2,0) DEF_WA(2,1) DEF_WA(2,2)
    DEF_WA(3,0) DEF_WA(3,1) DEF_WA(3,2)
#undef DEF_WA
    const float bA0 = (t < 140) ? c0b1[u] : 0.f;
    const float bA1 = (t < 140) ? c0b2[u] : 0.f;
    const float bA2 = (t < 140) ? c0ba[u] : 0.f;
    const float bA3 = (t < 140) ? c0bb[u] : 0.f;

    // ---- CfC1 weights: K2, replicated in EVERY wave (lanes l<46):
    //      unit cu1 = l>>1, half h1 = l&1, cols [32*h1, 32*h1+32) of 58
    const float *D0 = c1w1, *D1 = c1w2, *D2 = c1wa, *D3 = c1wb;
    auto c1f = [&](const float* Wp, int c) -> float {
        const int col = 32 * h1 + c;
        return (l < 46 && col < 58) ? Wp[cu1 * 58 + col] : 0.f;
    };
#define DEF_WD(A,q) \
    float wd##A##_##q##_0 = c1f(D##A, 4*q + 0); \
    float wd##A##_##q##_1 = c1f(D##A, 4*q + 1); \
    float wd##A##_##q##_2 = c1f(D##A, 4*q + 2); \
    float wd##A##_##q##_3 = c1f(D##A, 4*q + 3);
    DEF_WD(0,0) DEF_WD(0,1) DEF_WD(0,2) DEF_WD(0,3)
    DEF_WD(0,4) DEF_WD(0,5) DEF_WD(0,6) DEF_WD(0,7)
    DEF_WD(1,0) DEF_WD(1,1) DEF_WD(1,2) DEF_WD(1,3)
    DEF_WD(1,4) DEF_WD(1,5) DEF_WD(1,6) DEF_WD(1,7)
    DEF_WD(2,0) DEF_WD(2,1) DEF_WD(2,2) DEF_WD(2,3)
    DEF_WD(2,4) DEF_WD(2,5) DEF_WD(2,6) DEF_WD(2,7)
    DEF_WD(3,0) DEF_WD(3,1) DEF_WD(3,2) DEF_WD(3,3)
    DEF_WD(3,4) DEF_WD(3,5) DEF_WD(3,6) DEF_WD(3,7)
#undef DEF_WD
    const float bD0 = (l < 46) ? c1b1[cu1] : 0.f;
    const float bD1 = (l < 46) ? c1b2[cu1] : 0.f;
    const float bD2 = (l < 46) ? c1ba[cu1] : 0.f;
    const float bD3 = (l < 46) ? c1bb[cu1] : 0.f;

    // ---- CfC2 weights: K2, replicated in EVERY wave (lanes l in [46,58)):
    //      unit cu2, half h2, cols [16*h2, 16*h2+16) of 29
    const float *E0 = c2w1, *E1 = c2w2, *E2 = c2wa, *E3 = c2wb;
    auto c2f = [&](const float* Wp, int c) -> float {
        const int col = 16 * h2 + c;
        return (c2i >= 0 && c2i < 12 && col < 29) ? Wp[cu2 * 29 + col] : 0.f;
    };
#define DEF_WE(A,q) \
    float we##A##_##q##_0 = c2f(E##A, 4*q + 0); \
    float we##A##_##q##_1 = c2f(E##A, 4*q + 1); \
    float we##A##_##q##_2 = c2f(E##A, 4*q + 2); \
    float we##A##_##q##_3 = c2f(E##A, 4*q + 3);
    DEF_WE(0,0) DEF_WE(0,1) DEF_WE(0,2) DEF_WE(0,3)
    DEF_WE(1,0) DEF_WE(1,1) DEF_WE(1,2) DEF_WE(1,3)
    DEF_WE(2,0) DEF_WE(2,1) DEF_WE(2,2) DEF_WE(2,3)
    DEF_WE(3,0) DEF_WE(3,1) DEF_WE(3,2) DEF_WE(3,3)
#undef DEF_WE
    const float bE0 = (c2i >= 0 && c2i < 12) ? c2b1[cu2] : 0.f;
    const float bE1 = (c2i >= 0 && c2i < 12) ? c2b2[cu2] : 0.f;
    const float bE2 = (c2i >= 0 && c2i < 12) ? c2ba[cu2] : 0.f;
    const float bE3 = (c2i >= 0 && c2i < 12) ? c2bb[cu2] : 0.f;

    float creg = 0.f;               // cell state, replicated per quad

    // ---- prologue: zero state region, load x tile 0 ----
    for (int i = t; i < 720; i += 256) smem[i] = 0.f;
    if (t < 208) {                  // 208 float4 = 64 steps x 13
        float4 xi = *(const float4*)(x + xbase + 4 * t);
        *(float4*)&xt0[4 * t] = xi;
    }
    __syncthreads();

    #pragma unroll 1
    for (int ts = -1; ts < TSTEPS; ++ts) {
        const int par0 = ts & 1;            // ts=-1 -> 1 (only dead slots)
        const int par1 = par0 ^ 1;
        const int lts  = ts & 63;
        const int tpar = (ts >> 6) & 1;
        const bool run = (ts >= 0);

        // ================= region B: CfC0 || tile mgmt || x-copy =========
        if (run && t < 140) {
            const float4* zc = (const float4*)(z0 + 48 * par0 + 12 * k);
            float4 v0 = zc[0], v1 = zc[1], v2 = zc[2];
            float a0 = 0.f, a1 = 0.f, a2 = 0.f, a3 = 0.f;
            FMA4(a0, wa0, 0, v0) FMA4(a0, wa0, 1, v1) FMA4(a0, wa0, 2, v2)
            FMA4(a1, wa1, 0, v0) FMA4(a1, wa1, 1, v1) FMA4(a1, wa1, 2, v2)
            FMA4(a2, wa2, 0, v0) FMA4(a2, wa2, 1, v1) FMA4(a2, wa2, 2, v2)
            FMA4(a3, wa3, 0, v0) FMA4(a3, wa3, 1, v1) FMA4(a3, wa3, 2, v2)
            BFLY4(a0) BFLY4(a1) BFLY4(a2) BFLY4(a3)
            a0 += bA0; a1 += bA1; a2 += bA2; a3 += bA3;
            float tg = fsig(a2 + a3);
            float f1 = ftanh(a0), f2 = ftanh(a1);
            float o = f1 + tg * (f2 - f1);
            if (k == 0) { zLa[13 + u] = o; z1[64 * par0 + u] = o; }
        } else if (t >= 140) {
            if (run && lts == 62 && (ts + 2) < TSTEPS) {
                // refill x tile [ts+2, ts+66) into buffer tpar^1
                int i = (t - 140) * 2;                 // lanes 140..243
                float* dst = tpar ? xt0 : xt1;
                const float* src = x + xbase + (long)(ts + 2) * 13;
                if (i < 208)     *(float4*)&dst[4*i]     = *(const float4*)(src + 4*i);
                if (i + 1 < 208) *(float4*)&dst[4*(i+1)] = *(const float4*)(src + 4*(i+1));
            }
            if (run && lts == 0 && ts > 0) {
                // flush out tile for steps [ts-64, ts) from buffer tpar^1
                int i = t - 140;
                if (i < 96) {
                    const float* src = tpar ? ot0 : ot1;
                    float4 v = *(const float4*)&src[4 * i];
                    *(float4*)(out + obase + (long)(ts - XT) * 6 + 4 * i) = v;
                }
            }
        }
        // x_{ts+1} commit into zLa (LSTM source) and z0[par1] (CfC0 source)
        if (t >= 140 && t < 166 && (ts + 1) < TSTEPS) {
            const int i = t - 140;
            const float* xb = (((ts + 1) >> 6) & 1) ? xt1 : xt0;
            const int c = (i < 13) ? i : (i - 13);
            const float xn = xb[((ts + 1) & 63) * 13 + c];
            if (i < 13) zLa[c] = xn;
            else        z0[48 * par1 + c] = xn;
        }
        __syncthreads();

        // ================= region C: CfC1 -> CfC2 -> LSTM (wave-sync) ====
        {
            // prefetch CfC1 operand (o0^ts | h1^ts), published at the barrier
            float4 y0, y1, y2, y3, y4, y5, y6, y7;
            if (l < 46) {
                const float4* zc = (const float4*)(z1 + 64 * par0 + 32 * h1);
                y0 = zc[0]; y1 = zc[1]; y2 = zc[2]; y3 = zc[3];
                y4 = zc[4]; y5 = zc[5]; y6 = zc[6]; y7 = zc[7];
            }
            // prefetch LSTM k<2 operand chunks ([x_{ts+1} | o0^ts]) early
            float4 q0, q1, q2, q3, q4, q5;
            if (k < 2) {
                const float4* zc = (const float4*)(zLa + 24 * k);
                q0 = zc[0]; q1 = zc[1]; q2 = zc[2];
                q3 = zc[3]; q4 = zc[4]; q5 = zc[5];
            }

            // ---- CfC1 (per-wave redundant, K2) ----
            if (run && l < 46) {
                float a0 = 0.f, a1 = 0.f, a2 = 0.f, a3 = 0.f;
                FMA4(a0, wd0, 0, y0) FMA4(a0, wd0, 1, y1) FMA4(a0, wd0, 2, y2) FMA4(a0, wd0, 3, y3)
                FMA4(a0, wd0, 4, y4) FMA4(a0, wd0, 5, y5) FMA4(a0, wd0, 6, y6) FMA4(a0, wd0, 7, y7)
                FMA4(a1, wd1, 0, y0) FMA4(a1, wd1, 1, y1) FMA4(a1, wd1, 2, y2) FMA4(a1, wd1, 3, y3)
                FMA4(a1, wd1, 4, y4) FMA4(a1, wd1, 5, y5) FMA4(a1, wd1, 6, y6) FMA4(a1, wd1, 7, y7)
                FMA4(a2, wd2, 0, y0) FMA4(a2, wd2, 1, y1) FMA4(a2, wd2, 2, y2) FMA4(a2, wd2, 3, y3)
                FMA4(a2, wd2, 4, y4) FMA4(a2, wd2, 5, y5) FMA4(a2, wd2, 6, y6) FMA4(a2, wd2, 7, y7)
                FMA4(a3, wd3, 0, y0) FMA4(a3, wd3, 1, y1) FMA4(a3, wd3, 2, y2) FMA4(a3, wd3, 3, y3)
                FMA4(a3, wd3, 4, y4) FMA4(a3, wd3, 5, y5) FMA4(a3, wd3, 6, y6) FMA4(a3, wd3, 7, y7)
                a0 += qxor1(a0); a1 += qxor1(a1); a2 += qxor1(a2); a3 += qxor1(a3);
                a0 += bD0; a1 += bD1; a2 += bD2; a3 += bD3;
                float tg = fsig(a2 + a3);
                float f1 = ftanh(a0), f2 = ftanh(a1);
                float o = f1 + tg * (f2 - f1);
                if (h1 == 0) {
                    z2[64 * w + 32 * par0 + cu1] = o;   // CfC2 source (own wave)
                    zLb[48 * w + cu1] = o;              // LSTM k>=2 source
                }
            }
            LDS_FENCE();

            // ---- CfC2 (per-wave redundant, K2) ----
            if (run && c2i >= 0 && c2i < 12) {
                const float4* zc = (const float4*)(z2 + 64 * w + 32 * par0 + 16 * h2);
                float4 v0 = zc[0], v1 = zc[1], v2 = zc[2], v3 = zc[3];
                float a0 = 0.f, a1 = 0.f, a2 = 0.f, a3 = 0.f;
                FMA4(a0, we0, 0, v0) FMA4(a0, we0, 1, v1) FMA4(a0, we0, 2, v2) FMA4(a0, we0, 3, v3)
                FMA4(a1, we1, 0, v0) FMA4(a1, we1, 1, v1) FMA4(a1, we1, 2, v2) FMA4(a1, we1, 3, v3)
                FMA4(a2, we2, 0, v0) FMA4(a2, we2, 1, v1) FMA4(a2, we2, 2, v2) FMA4(a2, we2, 3, v3)
                FMA4(a3, we3, 0, v0) FMA4(a3, we3, 1, v1) FMA4(a3, we3, 2, v2) FMA4(a3, we3, 3, v3)
                a0 += qxor1(a0); a1 += qxor1(a1); a2 += qxor1(a2); a3 += qxor1(a3);
                a0 += bE0; a1 += bE1; a2 += bE2; a3 += bE3;
                float tg = fsig(a2 + a3);
                float f1 = ftanh(a0), f2 = ftanh(a1);
                float o = f1 + tg * (f2 - f1);
                if (h2 == 0) {
                    zLb[48 * w + 23 + cu2] = o;         // zL cols 71..76
                    if (w == 0) {                       // out tile (LDS only)
                        float* ob = tpar ? ot1 : ot0;
                        ob[lts * 6 + cu2] = o;
                    }
                }
            }
            LDS_FENCE();

            // ---- LSTM^{ts+1} (all lanes, K4 quad split) ----
            if (k >= 2) {
                const float4* zc = (const float4*)(zLb + 48 * w + 24 * (k - 2));
                q0 = zc[0]; q1 = zc[1]; q2 = zc[2];
                q3 = zc[3]; q4 = zc[4]; q5 = zc[5];
            }
            {
                float a0 = 0.f, a1 = 0.f, a2 = 0.f, a3 = 0.f;
                FMA4(a0, wl0, 0, q0) FMA4(a0, wl0, 1, q1) FMA4(a0, wl0, 2, q2)
                FMA4(a0, wl0, 3, q3) FMA4(a0, wl0, 4, q4) FMA4(a0, wl0, 5, q5)
                FMA4(a1, wl1, 0, q0) FMA4(a1, wl1, 1, q1) FMA4(a1, wl1, 2, q2)
                FMA4(a1, wl1, 3, q3) FMA4(a1, wl1, 4, q4) FMA4(a1, wl1, 5, q5)
                FMA4(a2, wl2, 0, q0) FMA4(a2, wl2, 1, q1) FMA4(a2, wl2, 2, q2)
                FMA4(a2, wl2, 3, q3) FMA4(a2, wl2, 4, q4) FMA4(a2, wl2, 5, q5)
                FMA4(a3, wl3, 0, q0) FMA4(a3, wl3, 1, q1) FMA4(a3, wl3, 2, q2)
                FMA4(a3, wl3, 3, q3) FMA4(a3, wl3, 4, q4) FMA4(a3, wl3, 5, q5)
                BFLY4(a0) BFLY4(a1) BFLY4(a2) BFLY4(a3)
                a0 += bL0; a1 += bL1; a2 += bL2; a3 += bL3;   // ia, ig, fg, og
                float cn = creg * fsig(a2 + 1.f) + ftanh(a0) * fsig(a1);
                creg = cn;                      // bit-identical on all 4 quad lanes
                float hl = ftanh(cn) * fsig(a3);
                if (k == 0) {
                    if (u < 35)      z0[48 * par1 + 13 + u] = hl;   // h0
                    else if (u < 58) z1[64 * par1 + u]      = hl;   // h1
                    else {                                          // h2: 4 copies
                        const int j = 32 * par1 + 23 + (u - 58);
                        z2[j] = hl; z2[64 + j] = hl; z2[128 + j] = hl; z2[192 + j] = hl;
                    }
                }
            }
        }
        __syncthreads();
    }

    // ---- epilogue: flush the last out tile (steps 4032..4095, buffer 1) ----
    if (t < 96) {
        float4 v = *(const float4*)&ot1[4 * t];
        *(float4*)(out + obase + (long)(TSTEPS - XT) * 6 + 4 * t) = v;
    }
}

// ---- head: rewrite pred in place, write unc ----
#define S_GW1 0
#define S_GB1 192
#define S_GW2 224
#define S_GB2 320
#define S_AW1 323
#define S_AB1 515
#define S_AW2 547
#define S_AB2 643
#define S_UW1 646
#define S_UB1 742
#define S_UW2 758
#define S_UB2 854
#define S_TOT 860

__global__ __launch_bounds__(256)
void head_kernel(const float* __restrict__ gw1, const float* __restrict__ gb1,
                 const float* __restrict__ gw2, const float* __restrict__ gb2,
                 const float* __restrict__ aw1, const float* __restrict__ ab1,
                 const float* __restrict__ aw2, const float* __restrict__ ab2,
                 const float* __restrict__ uw1, const float* __restrict__ ub1,
                 const float* __restrict__ uw2, const float* __restrict__ ub2,
                 float* __restrict__ out)
{
    __shared__ float s[S_TOT];
    const int t = threadIdx.x;
    if (t < 192) { s[S_GW1 + t] = gw1[t]; s[S_AW1 + t] = aw1[t]; }
    if (t < 96)  { s[S_GW2 + t] = gw2[t]; s[S_AW2 + t] = aw2[t];
                   s[S_UW1 + t] = uw1[t]; s[S_UW2 + t] = uw2[t]; }
    if (t < 32)  { s[S_GB1 + t] = gb1[t]; s[S_AB1 + t] = ab1[t]; }
    if (t < 16)  { s[S_UB1 + t] = ub1[t]; }
    if (t < 3)   { s[S_GB2 + t] = gb2[t]; s[S_AB2 + t] = ab2[t]; }
    if (t < 6)   { s[S_UB2 + t] = ub2[t]; }
    __syncthreads();

    const long p = (long)blockIdx.x * 256 + t;   // < B*T exactly
    const long base = p * 6;
    float m0 = out[base+0], m1 = out[base+1], m2 = out[base+2];
    float m3 = out[base+3], m4 = out[base+4], m5 = out[base+5];

    float gy0 = s[S_GB2+0], gy1 = s[S_GB2+1], gy2 = s[S_GB2+2];
    float ac0 = s[S_AB2+0], ac1 = s[S_AB2+1], ac2 = s[S_AB2+2];
    #pragma unroll
    for (int i = 0; i < 32; ++i) {
        float hg = s[S_GB1+i] + s[S_GW1+i*6+0]*m0 + s[S_GW1+i*6+1]*m1
                 + s[S_GW1+i*6+2]*m2 + s[S_GW1+i*6+3]*m3
                 + s[S_GW1+i*6+4]*m4 + s[S_GW1+i*6+5]*m5;
        hg = ftanh(hg);
        gy0 += s[S_GW2+i]*hg; gy1 += s[S_GW2+32+i]*hg; gy2 += s[S_GW2+64+i]*hg;
        float ha = s[S_AB1+i] + s[S_AW1+i*6+0]*m0 + s[S_AW1+i*6+1]*m1
                 + s[S_AW1+i*6+2]*m2 + s[S_AW1+i*6+3]*m3
                 + s[S_AW1+i*6+4]*m4 + s[S_AW1+i*6+5]*m5;
        ha = ftanh(ha);
        ac0 += s[S_AW2+i]*ha; ac1 += s[S_AW2+32+i]*ha; ac2 += s[S_AW2+64+i]*ha;
    }
    float u0 = s[S_UB2+0], u1 = s[S_UB2+1], u2 = s[S_UB2+2];
    float u3 = s[S_UB2+3], u4 = s[S_UB2+4], u5 = s[S_UB2+5];
    #pragma unroll
    for (int i = 0; i < 16; ++i) {
        float hu = s[S_UB1+i] + s[S_UW1+i*6+0]*m0 + s[S_UW1+i*6+1]*m1
                 + s[S_UW1+i*6+2]*m2 + s[S_UW1+i*6+3]*m3
                 + s[S_UW1+i*6+4]*m4 + s[S_UW1+i*6+5]*m5;
        hu = fmaxf(hu, 0.f);
        u0 += s[S_UW2+i]*hu;      u1 += s[S_UW2+16+i]*hu; u2 += s[S_UW2+32+i]*hu;
        u3 += s[S_UW2+48+i]*hu;   u4 += s[S_UW2+64+i]*hu; u5 += s[S_UW2+80+i]*hu;
    }
    out[base+0] = gy0; out[base+1] = gy1; out[base+2] = gy2;
    out[base+3] = ac0; out[base+4] = ac1; out[base+5] = ac2;
    const long uoff = (long)BATCH * TSTEPS * 6;
    out[uoff+base+0] = fsoftplus(u0); out[uoff+base+1] = fsoftplus(u1);
    out[uoff+base+2] = fsoftplus(u2); out[uoff+base+3] = fsoftplus(u3);
    out[uoff+base+4] = fsoftplus(u4); out[uoff+base+5] = fsoftplus(u5);
}

extern "C" void kernel_launch(void* const* d_in, const int* in_sizes, int n_in,
                              void* d_out, int out_size, void* d_ws, size_t ws_size,
                              hipStream_t stream) {
    const float* x       = (const float*)d_in[0];
    const float* lstm_wi = (const float*)d_in[1];
    const float* lstm_wh = (const float*)d_in[2];
    const float* lstm_b  = (const float*)d_in[3];
    const float* c0w1 = (const float*)d_in[4];
    const float* c0w2 = (const float*)d_in[5];
    const float* c0wa = (const float*)d_in[6];
    const float* c0wb = (const float*)d_in[7];
    const float* c0b1 = (const float*)d_in[8];
    const float* c0b2 = (const float*)d_in[9];
    const float* c0ba = (const float*)d_in[10];
    const float* c0bb = (const float*)d_in[11];
    const float* c1w1 = (const float*)d_in[12];
    const float* c1w2 = (const float*)d_in[13];
    const float* c1wa = (const float*)d_in[14];
    const float* c1wb = (const float*)d_in[15];
    const float* c1b1 = (const float*)d_in[16];
    const float* c1b2 = (const float*)d_in[17];
    const float* c1ba = (const float*)d_in[18];
    const float* c1bb = (const float*)d_in[19];
    const float* c2w1 = (const float*)d_in[20];
    const float* c2w2 = (const float*)d_in[21];
    const float* c2wa = (const float*)d_in[22];
    const float* c2wb = (const float*)d_in[23];
    const float* c2b1 = (const float*)d_in[24];
    const float* c2b2 = (const float*)d_in[25];
    const float* c2ba = (const float*)d_in[26];
    const float* c2bb = (const float*)d_in[27];
    const float* gw1 = (const float*)d_in[28];
    const float* gb1 = (const float*)d_in[29];
    const float* gw2 = (const float*)d_in[30];
    const float* gb2 = (const float*)d_in[31];
    const float* aw1 = (const float*)d_in[32];
    const float* ab1 = (const float*)d_in[33];
    const float* aw2 = (const float*)d_in[34];
    const float* ab2 = (const float*)d_in[35];
    const float* uw1 = (const float*)d_in[36];
    const float* ub1 = (const float*)d_in[37];
    const float* uw2 = (const float*)d_in[38];
    const float* ub2 = (const float*)d_in[39];
    float* out = (float*)d_out;

    rnn_kernel<<<BATCH, 256, 0, stream>>>(x, lstm_wi, lstm_wh, lstm_b,
        c0w1, c0w2, c0wa, c0wb, c0b1, c0b2, c0ba, c0bb,
        c1w1, c1w2, c1wa, c1wb, c1b1, c1b2, c1ba, c1bb,
        c2w1, c2w2, c2wa, c2wb, c2b1, c2b2, c2ba, c2bb, out);

    head_kernel<<<(BATCH * TSTEPS) / 256, 256, 0, stream>>>(
        gw1, gb1, gw2, gb2, aw1, ab1, aw2, ab2, uw1, ub1, uw2, ub2, out);
}

// Round 2
// 5597.813 us; speedup vs baseline: 1.4731x; 1.4731x over previous
//
#include <hip/hip_runtime.h>
#include <math.h>

#define BATCH 128
#define TSTEPS 4096
#define INDIM 13
#define XT 64   // steps per x/out LDS tile

// ============================================================================
// 3-phase schedule (was 4). Per step ts:
//   P1: CfC2^{ts-1} (wave-redundant, lanes l in [40,64) of EVERY wave, K4,
//       32 FMA, zero-masked weights elsewhere -- branchless, interleaves with
//       LSTM^{ts} early dot) ; wave-local fence ; LSTM^{ts} late o2 cols +
//       BFLY + nonlin + h writes.
//   P2: CfC0^{ts} (lanes 0..139) || x-tile refill / out flush ||
//       x_{ts+1} commit (lanes 192..204, parity z0)
//   P3: CfC1^{ts} (lanes 140..231)
// zL[71..96) stays permanently ZERO so the baseline LSTM read/FMA stream is
// unchanged for the early pass (o2 cols contribute 0); late o2 FMAs use the
// same weight registers (k==2: col 71, k==3: cols 72..76).
//
// LDS layout (floats):
//   zL  @0    : 96  [x(13)|o0(35)|o1(23)|zero(25)]
//   z0  @96   : 2x48 parity [x|h0]
//   z1  @192  : 64  [o0(35)|h1(23)|zero(6)]
//   z2h @256  : 2x8 parity h2 (LSTM writes par0, CfC2 reads par1)
//   zLw @272  : 4x8 per-wave o2 (wave-local, lgkmcnt-fenced)
//   xt0 @304 (832) | xt1 @1136 (832)   x tiles, double-buffered
//   ot0 @1968 (384) | ot1 @2352 (384)  out tiles, double-buffered
// ============================================================================

__device__ __forceinline__ float fsig(float x) {
    return __builtin_amdgcn_rcpf(1.f + __expf(-x));
}
__device__ __forceinline__ float ftanh(float x) {
    float s = fsig(x + x);
    return s + s - 1.f;
}
__device__ __forceinline__ float fsoftplus(float x) {
    return (x > 15.f) ? x : __logf(1.f + __expf(x));
}

// quad exchanges via DPP (VALU latency, no LDS pipe)
__device__ __forceinline__ float qxor1(float v) {   // quad_perm [1,0,3,2]
    return __int_as_float(__builtin_amdgcn_update_dpp(
        0, __float_as_int(v), 0xB1, 0xF, 0xF, true));
}
__device__ __forceinline__ float qxor2(float v) {   // quad_perm [2,3,0,1]
    return __int_as_float(__builtin_amdgcn_update_dpp(
        0, __float_as_int(v), 0x4E, 0xF, 0xF, true));
}
// 4-lane butterfly allreduce, 2 DPP stages, bit-identical on all 4 lanes.
#define BFLY4(a) { a += qxor1(a); a += qxor2(a); }

// acc += dot(float4 zv, 4 named weight scalars W_q_{0..3})
#define FMA4(acc, W, q, zv) { acc += zv.x * W##_##q##_0; acc += zv.y * W##_##q##_1; \
                              acc += zv.z * W##_##q##_2; acc += zv.w * W##_##q##_3; }

// intra-wave producer->consumer fence (same-wave DS ordering + sched fence)
#define LDS_FENCE() { asm volatile("s_waitcnt lgkmcnt(0)" ::: "memory"); \
                      __builtin_amdgcn_sched_barrier(0); }

__global__ __launch_bounds__(256, 1)
void rnn_kernel(const float* __restrict__ x,
                const float* __restrict__ lstm_wi, const float* __restrict__ lstm_wh,
                const float* __restrict__ lstm_b,
                const float* __restrict__ c0w1, const float* __restrict__ c0w2,
                const float* __restrict__ c0wa, const float* __restrict__ c0wb,
                const float* __restrict__ c0b1, const float* __restrict__ c0b2,
                const float* __restrict__ c0ba, const float* __restrict__ c0bb,
                const float* __restrict__ c1w1, const float* __restrict__ c1w2,
                const float* __restrict__ c1wa, const float* __restrict__ c1wb,
                const float* __restrict__ c1b1, const float* __restrict__ c1b2,
                const float* __restrict__ c1ba, const float* __restrict__ c1bb,
                const float* __restrict__ c2w1, const float* __restrict__ c2w2,
                const float* __restrict__ c2wa, const float* __restrict__ c2wb,
                const float* __restrict__ c2b1, const float* __restrict__ c2b2,
                const float* __restrict__ c2ba, const float* __restrict__ c2bb,
                float* __restrict__ out)
{
    const int bb = blockIdx.x;
    const int t  = threadIdx.x;     // 0..255
    const int k  = t & 3;           // K-chunk slot within the quad
    const int u  = t >> 2;          // unit / row-group index 0..63
    const int l  = t & 63;          // lane within wave
    const int w  = t >> 6;          // wave index 0..3

    __shared__ __align__(16) float smem[2736];
    float* zL  = smem;
    float* z0  = smem + 96;
    float* z1  = smem + 192;
    float* z2h = smem + 256;
    float* zLw = smem + 272;
    float* xt0 = smem + 304;
    float* xt1 = smem + 1136;
    float* ot0 = smem + 1968;
    float* ot1 = smem + 2352;

    const long xbase = (long)bb * TSTEPS * INDIM;
    const long obase = (long)bb * TSTEPS * 6;

    // ---- LSTM weights: lane (u,k) holds cols [24k,24k+24) of all 4 gate rows
    auto lwf = [&](int A, int c) -> float {
        int r = A * 64 + u;
        return (c < 13) ? lstm_wi[r * 13 + c]
             : (c < 77) ? lstm_wh[r * 64 + (c - 13)] : 0.f;
    };
#define DEF_WL(A,q) \
    float wl##A##_##q##_0 = lwf(A, 24*k + 4*q + 0); \
    float wl##A##_##q##_1 = lwf(A, 24*k + 4*q + 1); \
    float wl##A##_##q##_2 = lwf(A, 24*k + 4*q + 2); \
    float wl##A##_##q##_3 = lwf(A, 24*k + 4*q + 3);
    DEF_WL(0,0) DEF_WL(0,1) DEF_WL(0,2) DEF_WL(0,3) DEF_WL(0,4) DEF_WL(0,5)
    DEF_WL(1,0) DEF_WL(1,1) DEF_WL(1,2) DEF_WL(1,3) DEF_WL(1,4) DEF_WL(1,5)
    DEF_WL(2,0) DEF_WL(2,1) DEF_WL(2,2) DEF_WL(2,3) DEF_WL(2,4) DEF_WL(2,5)
    DEF_WL(3,0) DEF_WL(3,1) DEF_WL(3,2) DEF_WL(3,3) DEF_WL(3,4) DEF_WL(3,5)
#undef DEF_WL
    const float bL0 = lstm_b[u];
    const float bL1 = lstm_b[64 + u];
    const float bL2 = lstm_b[128 + u];
    const float bL3 = lstm_b[192 + u];

    // ---- CfC0/CfC1 weights: quad groups (disjoint lane sets, one name overlay)
    // grp0 (u<35):  row u,    len 48, chunk 12 at 12k (3 float4)
    // grp1 (u<58):  row u-35, len 58, chunk 16 at 16k (4 float4)
    const int grp  = (u < 35) ? 0 : (u < 58) ? 1 : 2;
    const int row  = (grp == 0) ? u : (grp == 1) ? (u - 35) : (u - 58);
    const int rl   = (grp == 0) ? 48 : (grp == 1) ? 58 : 29;
    const int clen = (grp == 0) ? 12 : (grp == 1) ? 16 : 8;
    const int cb   = clen * k;
    const float *W0p, *W1p, *W2p, *W3p;
    float bC0, bC1, bC2, bC3;
    if (grp == 0) {
        W0p = c0w1 + row * 48; W1p = c0w2 + row * 48;
        W2p = c0wa + row * 48; W3p = c0wb + row * 48;
        bC0 = c0b1[row]; bC1 = c0b2[row]; bC2 = c0ba[row]; bC3 = c0bb[row];
    } else if (grp == 1) {
        W0p = c1w1 + row * 58; W1p = c1w2 + row * 58;
        W2p = c1wa + row * 58; W3p = c1wb + row * 58;
        bC0 = c1b1[row]; bC1 = c1b2[row]; bC2 = c1ba[row]; bC3 = c1bb[row];
    } else {
        W0p = c2w1 + row * 29; W1p = c2w2 + row * 29;
        W2p = c2wa + row * 29; W3p = c2wb + row * 29;
        bC0 = c2b1[row]; bC1 = c2b2[row]; bC2 = c2ba[row]; bC3 = c2bb[row];
    }
    auto cwf = [&](const float* W, int c) -> float {
        int cc = cb + c;
        return (c < clen && cc < rl) ? W[cc] : 0.f;
    };
#define DEF_WC(A,q) \
    float wc##A##_##q##_0 = cwf(W##A##p, 4*q + 0); \
    float wc##A##_##q##_1 = cwf(W##A##p, 4*q + 1); \
    float wc##A##_##q##_2 = cwf(W##A##p, 4*q + 2); \
    float wc##A##_##q##_3 = cwf(W##A##p, 4*q + 3);
    DEF_WC(0,0) DEF_WC(0,1) DEF_WC(0,2) DEF_WC(0,3)
    DEF_WC(1,0) DEF_WC(1,1) DEF_WC(1,2) DEF_WC(1,3)
    DEF_WC(2,0) DEF_WC(2,1) DEF_WC(2,2) DEF_WC(2,3)
    DEF_WC(3,0) DEF_WC(3,1) DEF_WC(3,2) DEF_WC(3,3)
#undef DEF_WC

    // ---- CfC2 weights for wave-redundant P1 compute: lanes l in [40,64) of
    // every wave: unit c2u=(l-40)>>2, K4 slot c2k=(l-40)&3.
    // slots: c2k<3 -> operand zL[48+8*c2k ..), weight col 8*c2k+j (<23 = o1)
    //        c2k=3 -> operand z2h[8*par1 ..), weight col 23+j (<29 = h2)
    const int c2a = (l >= 40) ? 1 : 0;
    const int c2k = c2a ? ((l - 40) & 3) : 0;
    const int c2u = c2a ? ((l - 40) >> 2) : 0;
    auto gwf = [&](const float* W, int j) -> float {
        int col = (c2k < 3) ? (8 * c2k + j) : (23 + j);
        int lim = (c2k < 3) ? 23 : 29;
        return (c2a && col < lim) ? W[c2u * 29 + col] : 0.f;
    };
#define DEF_WG(A,q) \
    float wg##A##_##q##_0 = gwf(G##A, 4*q + 0); \
    float wg##A##_##q##_1 = gwf(G##A, 4*q + 1); \
    float wg##A##_##q##_2 = gwf(G##A, 4*q + 2); \
    float wg##A##_##q##_3 = gwf(G##A, 4*q + 3);
    const float *G0 = c2w1, *G1 = c2w2, *G2 = c2wa, *G3 = c2wb;
    DEF_WG(0,0) DEF_WG(0,1)
    DEF_WG(1,0) DEF_WG(1,1)
    DEF_WG(2,0) DEF_WG(2,1)
    DEF_WG(3,0) DEF_WG(3,1)
#undef DEF_WG
    const float bE0 = c2a ? c2b1[c2u] : 0.f;
    const float bE1 = c2a ? c2b2[c2u] : 0.f;
    const float bE2 = c2a ? c2ba[c2u] : 0.f;
    const float bE3 = c2a ? c2bb[c2u] : 0.f;

    float creg = 0.f;                         // cell state, replicated per quad

    // ---- prologue: zero state region, load x tile 0, seed x_0 ----
    for (int i = t; i < 304; i += 256) smem[i] = 0.f;
    if (t < 208) {                            // 208 float4 = 64 steps x 13
        float4 xi = *(const float4*)(x + xbase + 4 * t);
        *(float4*)&xt0[4 * t] = xi;
    }
    if (t < 13) { float x0v = x[xbase + t]; zL[t] = x0v; z0[t] = x0v; }
    __syncthreads();

    #pragma unroll 1
    for (int ts = 0; ts < TSTEPS; ++ts) {
        const int par0 = ts & 1;
        const int par1 = par0 ^ 1;
        const int lts  = ts & 63;
        const int tpar = (ts >> 6) & 1;

        // ====== P1: CfC2^{ts-1} (wave-redundant) + LSTM^{ts} ======
        {
            // CfC2 operand (o1^{ts-1} from zL[48..71)+zero71, h2^{ts-1} parity)
            const float* cp = (c2k < 3) ? (zL + 48 + 8 * c2k) : (z2h + 8 * par1);
            float4 cv0 = ((const float4*)cp)[0];
            float4 cv1 = ((const float4*)cp)[1];
            // LSTM early operand (zL[71..96) permanently zero)
            const float4* zc = (const float4*)(zL + 24 * k);
            float4 q0 = zc[0], q1 = zc[1], q2 = zc[2],
                   q3 = zc[3], q4 = zc[4], q5 = zc[5];

            // CfC2 dot (32 FMA, zero weights on lanes l<40)
            float g0 = 0.f, g1 = 0.f, g2 = 0.f, g3 = 0.f;
            FMA4(g0, wg0, 0, cv0) FMA4(g0, wg0, 1, cv1)
            FMA4(g1, wg1, 0, cv0) FMA4(g1, wg1, 1, cv1)
            FMA4(g2, wg2, 0, cv0) FMA4(g2, wg2, 1, cv1)
            FMA4(g3, wg3, 0, cv0) FMA4(g3, wg3, 1, cv1)

            // LSTM early dot (96 FMA) -- interleaves with CfC2 chain
            float a0 = 0.f, a1 = 0.f, a2 = 0.f, a3 = 0.f;
            FMA4(a0, wl0, 0, q0) FMA4(a0, wl0, 1, q1) FMA4(a0, wl0, 2, q2)
            FMA4(a0, wl0, 3, q3) FMA4(a0, wl0, 4, q4) FMA4(a0, wl0, 5, q5)
            FMA4(a1, wl1, 0, q0) FMA4(a1, wl1, 1, q1) FMA4(a1, wl1, 2, q2)
            FMA4(a1, wl1, 3, q3) FMA4(a1, wl1, 4, q4) FMA4(a1, wl1, 5, q5)
            FMA4(a2, wl2, 0, q0) FMA4(a2, wl2, 1, q1) FMA4(a2, wl2, 2, q2)
            FMA4(a2, wl2, 3, q3) FMA4(a2, wl2, 4, q4) FMA4(a2, wl2, 5, q5)
            FMA4(a3, wl3, 0, q0) FMA4(a3, wl3, 1, q1) FMA4(a3, wl3, 2, q2)
            FMA4(a3, wl3, 3, q3) FMA4(a3, wl3, 4, q4) FMA4(a3, wl3, 5, q5)

            // CfC2 finish
            BFLY4(g0) BFLY4(g1) BFLY4(g2) BFLY4(g3)
            g0 += bE0; g1 += bE1; g2 += bE2; g3 += bE3;
            float tg2 = fsig(g2 + g3);
            float f1g = ftanh(g0), f2g = ftanh(g1);
            float og  = f1g + tg2 * (f2g - f1g);
            if (ts > 0 && c2a && ((l - 40) & 3) == 0) {
                zLw[8 * w + c2u] = og;              // wave-local o2
                if (w == 0) {                       // out tile (step ts-1)
                    float* ob = (((ts - 1) >> 6) & 1) ? ot1 : ot0;
                    ob[((ts - 1) & 63) * 6 + c2u] = og;
                }
            }
            LDS_FENCE();

            // LSTM late: o2 columns 71..76 (reuse existing weight registers)
            float4 oza = *(const float4*)(zLw + 8 * w);
            float2 ozb = *(const float2*)(zLw + 8 * w + 4);
            if (k == 2) {
                a0 += oza.x * wl0_5_3; a1 += oza.x * wl1_5_3;
                a2 += oza.x * wl2_5_3; a3 += oza.x * wl3_5_3;
            } else if (k == 3) {
                a0 += oza.y * wl0_0_0; a0 += oza.z * wl0_0_1; a0 += oza.w * wl0_0_2;
                a0 += ozb.x * wl0_0_3; a0 += ozb.y * wl0_1_0;
                a1 += oza.y * wl1_0_0; a1 += oza.z * wl1_0_1; a1 += oza.w * wl1_0_2;
                a1 += ozb.x * wl1_0_3; a1 += ozb.y * wl1_1_0;
                a2 += oza.y * wl2_0_0; a2 += oza.z * wl2_0_1; a2 += oza.w * wl2_0_2;
                a2 += ozb.x * wl2_0_3; a2 += ozb.y * wl2_1_0;
                a3 += oza.y * wl3_0_0; a3 += oza.z * wl3_0_1; a3 += oza.w * wl3_0_2;
                a3 += ozb.x * wl3_0_3; a3 += ozb.y * wl3_1_0;
            }
            BFLY4(a0) BFLY4(a1) BFLY4(a2) BFLY4(a3)
            a0 += bL0; a1 += bL1; a2 += bL2; a3 += bL3;   // ia, ig, fg, og
            float cn = creg * fsig(a2 + 1.f) + ftanh(a0) * fsig(a1);
            creg = cn;                      // bit-identical on all 4 quad lanes
            float hl = ftanh(cn) * fsig(a3);
            if (k == 0) {
                if (u < 35)      z0[48 * par0 + 13 + u] = hl;   // h0
                else if (u < 58) z1[u] = hl;                    // h1
                else             z2h[8 * par0 + (u - 58)] = hl; // h2 (parity)
            }
        }
        __syncthreads();

        // ====== P2: CfC0 (lanes 0..139) || tile refill / flush || x-commit ==
        if (t < 140) {
            const float4* zc = (const float4*)(z0 + 48 * par0 + 12 * k);
            float4 v0 = zc[0], v1 = zc[1], v2 = zc[2];
            float a0 = 0.f, a1 = 0.f, a2 = 0.f, a3 = 0.f;
            FMA4(a0, wc0, 0, v0) FMA4(a0, wc0, 1, v1) FMA4(a0, wc0, 2, v2)
            FMA4(a1, wc1, 0, v0) FMA4(a1, wc1, 1, v1) FMA4(a1, wc1, 2, v2)
            FMA4(a2, wc2, 0, v0) FMA4(a2, wc2, 1, v1) FMA4(a2, wc2, 2, v2)
            FMA4(a3, wc3, 0, v0) FMA4(a3, wc3, 1, v1) FMA4(a3, wc3, 2, v2)
            BFLY4(a0) BFLY4(a1) BFLY4(a2) BFLY4(a3)
            a0 += bC0; a1 += bC1; a2 += bC2; a3 += bC3;
            float tg = fsig(a2 + a3);
            float f1 = ftanh(a0), f2 = ftanh(a1);
            float o = f1 + tg * (f2 - f1);
            if (k == 0) { z1[row] = o; zL[13 + row] = o; }
        } else {
            if (lts == 62 && (ts + 2) < TSTEPS) {
                // refill x tile [ts+2, ts+66) into buffer tpar^1 (2 f4/lane)
                int i = (t - 140) * 2;                 // lanes 140..243
                float* dst = tpar ? xt0 : xt1;
                const float* src = x + xbase + (long)(ts + 2) * 13;
                if (i < 208)     *(float4*)&dst[4*i]     = *(const float4*)(src + 4*i);
                if (i + 1 < 208) *(float4*)&dst[4*(i+1)] = *(const float4*)(src + 4*(i+1));
            }
            if (lts == 0 && ts > 0) {
                // flush out tile for steps [ts-64, ts) from buffer tpar^1
                int i = t - 140;                       // 0..95 used
                if (i < 96) {
                    const float* src = tpar ? ot0 : ot1;
                    float4 v = *(const float4*)&src[4 * i];
                    *(float4*)(out + obase + (long)(ts - XT) * 6 + 4 * i) = v;
                }
            }
        }
        if (t >= 192 && t < 205 && (ts + 1) < TSTEPS) {
            // commit x_{ts+1} into zL (LSTM^{ts+1} source) and z0[par1]
            const int i = t - 192;
            const float* xb = (((ts + 1) >> 6) & 1) ? xt1 : xt0;
            float xn = xb[((ts + 1) & 63) * 13 + i];
            zL[i] = xn; z0[48 * par1 + i] = xn;
        }
        __syncthreads();

        // ====== P3: CfC1 (lanes 140..231) ======
        if (grp == 1) {
            const float4* zc = (const float4*)(z1 + 16 * k);
            float4 v0 = zc[0], v1 = zc[1], v2 = zc[2], v3 = zc[3];
            float a0 = 0.f, a1 = 0.f, a2 = 0.f, a3 = 0.f;
            FMA4(a0, wc0, 0, v0) FMA4(a0, wc0, 1, v1) FMA4(a0, wc0, 2, v2) FMA4(a0, wc0, 3, v3)
            FMA4(a1, wc1, 0, v0) FMA4(a1, wc1, 1, v1) FMA4(a1, wc1, 2, v2) FMA4(a1, wc1, 3, v3)
            FMA4(a2, wc2, 0, v0) FMA4(a2, wc2, 1, v1) FMA4(a2, wc2, 2, v2) FMA4(a2, wc2, 3, v3)
            FMA4(a3, wc3, 0, v0) FMA4(a3, wc3, 1, v1) FMA4(a3, wc3, 2, v2) FMA4(a3, wc3, 3, v3)
            BFLY4(a0) BFLY4(a1) BFLY4(a2) BFLY4(a3)
            a0 += bC0; a1 += bC1; a2 += bC2; a3 += bC3;
            float tg = fsig(a2 + a3);
            float f1 = ftanh(a0), f2 = ftanh(a1);
            float o = f1 + tg * (f2 - f1);
            if (k == 0) { zL[48 + row] = o; }          // o1 (cols 48..71)
        }
        __syncthreads();
    }

    // ---- epilogue: CfC2^{4095} (all waves, wave 0 writes), then flush ----
    {
        const float* cp = (c2k < 3) ? (zL + 48 + 8 * c2k) : (z2h + 8);  // par0(4095)=1
        float4 cv0 = ((const float4*)cp)[0];
        float4 cv1 = ((const float4*)cp)[1];
        float g0 = 0.f, g1 = 0.f, g2 = 0.f, g3 = 0.f;
        FMA4(g0, wg0, 0, cv0) FMA4(g0, wg0, 1, cv1)
        FMA4(g1, wg1, 0, cv0) FMA4(g1, wg1, 1, cv1)
        FMA4(g2, wg2, 0, cv0) FMA4(g2, wg2, 1, cv1)
        FMA4(g3, wg3, 0, cv0) FMA4(g3, wg3, 1, cv1)
        BFLY4(g0) BFLY4(g1) BFLY4(g2) BFLY4(g3)
        g0 += bE0; g1 += bE1; g2 += bE2; g3 += bE3;
        float tg2 = fsig(g2 + g3);
        float f1g = ftanh(g0), f2g = ftanh(g1);
        float og  = f1g + tg2 * (f2g - f1g);
        if (c2a && ((l - 40) & 3) == 0 && w == 0)
            ot1[63 * 6 + c2u] = og;
    }
    __syncthreads();
    if (t < 96) {
        float4 v = *(const float4*)&ot1[4 * t];
        *(float4*)(out + obase + (long)(TSTEPS - XT) * 6 + 4 * t) = v;
    }
}

// ---- head: rewrite pred in place, write unc ----
#define S_GW1 0
#define S_GB1 192
#define S_GW2 224
#define S_GB2 320
#define S_AW1 323
#define S_AB1 515
#define S_AW2 547
#define S_AB2 643
#define S_UW1 646
#define S_UB1 742
#define S_UW2 758
#define S_UB2 854
#define S_TOT 860

__global__ __launch_bounds__(256)
void head_kernel(const float* __restrict__ gw1, const float* __restrict__ gb1,
                 const float* __restrict__ gw2, const float* __restrict__ gb2,
                 const float* __restrict__ aw1, const float* __restrict__ ab1,
                 const float* __restrict__ aw2, const float* __restrict__ ab2,
                 const float* __restrict__ uw1, const float* __restrict__ ub1,
                 const float* __restrict__ uw2, const float* __restrict__ ub2,
                 float* __restrict__ out)
{
    __shared__ float s[S_TOT];
    const int t = threadIdx.x;
    if (t < 192) { s[S_GW1 + t] = gw1[t]; s[S_AW1 + t] = aw1[t]; }
    if (t < 96)  { s[S_GW2 + t] = gw2[t]; s[S_AW2 + t] = aw2[t];
                   s[S_UW1 + t] = uw1[t]; s[S_UW2 + t] = uw2[t]; }
    if (t < 32)  { s[S_GB1 + t] = gb1[t]; s[S_AB1 + t] = ab1[t]; }
    if (t < 16)  { s[S_UB1 + t] = ub1[t]; }
    if (t < 3)   { s[S_GB2 + t] = gb2[t]; s[S_AB2 + t] = ab2[t]; }
    if (t < 6)   { s[S_UB2 + t] = ub2[t]; }
    __syncthreads();

    const long p = (long)blockIdx.x * 256 + t;   // < B*T exactly
    const long base = p * 6;
    float m0 = out[base+0], m1 = out[base+1], m2 = out[base+2];
    float m3 = out[base+3], m4 = out[base+4], m5 = out[base+5];

    float gy0 = s[S_GB2+0], gy1 = s[S_GB2+1], gy2 = s[S_GB2+2];
    float ac0 = s[S_AB2+0], ac1 = s[S_AB2+1], ac2 = s[S_AB2+2];
    #pragma unroll
    for (int i = 0; i < 32; ++i) {
        float hg = s[S_GB1+i] + s[S_GW1+i*6+0]*m0 + s[S_GW1+i*6+1]*m1
                 + s[S_GW1+i*6+2]*m2 + s[S_GW1+i*6+3]*m3
                 + s[S_GW1+i*6+4]*m4 + s[S_GW1+i*6+5]*m5;
        hg = ftanh(hg);
        gy0 += s[S_GW2+i]*hg; gy1 += s[S_GW2+32+i]*hg; gy2 += s[S_GW2+64+i]*hg;
        float ha = s[S_AB1+i] + s[S_AW1+i*6+0]*m0 + s[S_AW1+i*6+1]*m1
                 + s[S_AW1+i*6+2]*m2 + s[S_AW1+i*6+3]*m3
                 + s[S_AW1+i*6+4]*m4 + s[S_AW1+i*6+5]*m5;
        ha = ftanh(ha);
        ac0 += s[S_AW2+i]*ha; ac1 += s[S_AW2+32+i]*ha; ac2 += s[S_AW2+64+i]*ha;
    }
    float u0 = s[S_UB2+0], u1 = s[S_UB2+1], u2 = s[S_UB2+2];
    float u3 = s[S_UB2+3], u4 = s[S_UB2+4], u5 = s[S_UB2+5];
    #pragma unroll
    for (int i = 0; i < 16; ++i) {
        float hu = s[S_UB1+i] + s[S_UW1+i*6+0]*m0 + s[S_UW1+i*6+1]*m1
                 + s[S_UW1+i*6+2]*m2 + s[S_UW1+i*6+3]*m3
                 + s[S_UW1+i*6+4]*m4 + s[S_UW1+i*6+5]*m5;
        hu = fmaxf(hu, 0.f);
        u0 += s[S_UW2+i]*hu;      u1 += s[S_UW2+16+i]*hu; u2 += s[S_UW2+32+i]*hu;
        u3 += s[S_UW2+48+i]*hu;   u4 += s[S_UW2+64+i]*hu; u5 += s[S_UW2+80+i]*hu;
    }
    out[base+0] = gy0; out[base+1] = gy1; out[base+2] = gy2;
    out[base+3] = ac0; out[base+4] = ac1; out[base+5] = ac2;
    const long uoff = (long)BATCH * TSTEPS * 6;
    out[uoff+base+0] = fsoftplus(u0); out[uoff+base+1] = fsoftplus(u1);
    out[uoff+base+2] = fsoftplus(u2); out[uoff+base+3] = fsoftplus(u3);
    out[uoff+base+4] = fsoftplus(u4); out[uoff+base+5] = fsoftplus(u5);
}

extern "C" void kernel_launch(void* const* d_in, const int* in_sizes, int n_in,
                              void* d_out, int out_size, void* d_ws, size_t ws_size,
                              hipStream_t stream) {
    const float* x       = (const float*)d_in[0];
    const float* lstm_wi = (const float*)d_in[1];
    const float* lstm_wh = (const float*)d_in[2];
    const float* lstm_b  = (const float*)d_in[3];
    const float* c0w1 = (const float*)d_in[4];
    const float* c0w2 = (const float*)d_in[5];
    const float* c0wa = (const float*)d_in[6];
    const float* c0wb = (const float*)d_in[7];
    const float* c0b1 = (const float*)d_in[8];
    const float* c0b2 = (const float*)d_in[9];
    const float* c0ba = (const float*)d_in[10];
    const float* c0bb = (const float*)d_in[11];
    const float* c1w1 = (const float*)d_in[12];
    const float* c1w2 = (const float*)d_in[13];
    const float* c1wa = (const float*)d_in[14];
    const float* c1wb = (const float*)d_in[15];
    const float* c1b1 = (const float*)d_in[16];
    const float* c1b2 = (const float*)d_in[17];
    const float* c1ba = (const float*)d_in[18];
    const float* c1bb = (const float*)d_in[19];
    const float* c2w1 = (const float*)d_in[20];
    const float* c2w2 = (const float*)d_in[21];
    const float* c2wa = (const float*)d_in[22];
    const float* c2wb = (const float*)d_in[23];
    const float* c2b1 = (const float*)d_in[24];
    const float* c2b2 = (const float*)d_in[25];
    const float* c2ba = (const float*)d_in[26];
    const float* c2bb = (const float*)d_in[27];
    const float* gw1 = (const float*)d_in[28];
    const float* gb1 = (const float*)d_in[29];
    const float* gw2 = (const float*)d_in[30];
    const float* gb2 = (const float*)d_in[31];
    const float* aw1 = (const float*)d_in[32];
    const float* ab1 = (const float*)d_in[33];
    const float* aw2 = (const float*)d_in[34];
    const float* ab2 = (const float*)d_in[35];
    const float* uw1 = (const float*)d_in[36];
    const float* ub1 = (const float*)d_in[37];
    const float* uw2 = (const float*)d_in[38];
    const float* ub2 = (const float*)d_in[39];
    float* out = (float*)d_out;

    rnn_kernel<<<BATCH, 256, 0, stream>>>(x, lstm_wi, lstm_wh, lstm_b,
        c0w1, c0w2, c0wa, c0wb, c0b1, c0b2, c0ba, c0bb,
        c1w1, c1w2, c1wa, c1wb, c1b1, c1b2, c1ba, c1bb,
        c2w1, c2w2, c2wa, c2wb, c2b1, c2b2, c2ba, c2bb, out);

    head_kernel<<<(BATCH * TSTEPS) / 256, 256, 0, stream>>>(
        gw1, gb1, gw2, gb2, aw1, ab1, aw2, ab2, uw1, ub1, uw2, ub2, out);
}

// Round 3
// 5294.637 us; speedup vs baseline: 1.5575x; 1.0573x over previous
//
#include <hip/hip_runtime.h>
#include <math.h>

#define BATCH 128
#define TSTEPS 4096
#define INDIM 13
#define XT 64   // steps per x/out LDS tile

// LDS layout (floats):
//  state[0:256):  zL[0:96) | z0 @96 | z1 @160 | z2 @224   (zero-initialized)
//  xt0 @256 (832) | xt1 @1088 (832)   x tiles, double-buffered (64 steps x 13)
//  ot0 @1920 (384) | ot1 @2304 (384)  out tiles, double-buffered (64 steps x 6)
// 256 threads (4 waves, 1 wave/SIMD via __launch_bounds__(256,1)): quad
// K-split, 2-DPP butterfly, no global memory in the steady-state loop.
//
// R3 change vs R0: every weight/bias scalar is pinned into a VGPR with an
// empty asm ("+v") after load. R0's VGPR_Count=108 < 168 named weights proved
// the compiler was rematerializing weight loads inside the 4096-step loop
// (per-step VMEM reloads in every phase). Pinning makes remat illegal.

__device__ __forceinline__ float fsig(float x) {
    return __builtin_amdgcn_rcpf(1.f + __expf(-x));
}
__device__ __forceinline__ float ftanh(float x) {
    float s = fsig(x + x);
    return s + s - 1.f;
}
__device__ __forceinline__ float fsoftplus(float x) {
    return (x > 15.f) ? x : __logf(1.f + __expf(x));
}

// quad exchanges via DPP (VALU latency, no LDS pipe)
__device__ __forceinline__ float qxor1(float v) {   // quad_perm [1,0,3,2]
    return __int_as_float(__builtin_amdgcn_update_dpp(
        0, __float_as_int(v), 0xB1, 0xF, 0xF, true));
}
__device__ __forceinline__ float qxor2(float v) {   // quad_perm [2,3,0,1]
    return __int_as_float(__builtin_amdgcn_update_dpp(
        0, __float_as_int(v), 0x4E, 0xF, 0xF, true));
}
// 4-lane butterfly allreduce, 2 DPP stages, bit-identical on all 4 lanes.
#define BFLY4(a) { a += qxor1(a); a += qxor2(a); }

// acc += dot(float4 zv, 4 named weight scalars W_q_{0..3})
#define FMA4(acc, W, q, zv) { acc += zv.x * W##_##q##_0; acc += zv.y * W##_##q##_1; \
                              acc += zv.z * W##_##q##_2; acc += zv.w * W##_##q##_3; }

// pin a float into a VGPR: opaque to the optimizer -> no rematerialization,
// value stays register-resident across the whole timestep loop.
#define PINF(v) asm volatile("" : "+v"(v));

__global__ __launch_bounds__(256, 1)
void rnn_kernel(const float* __restrict__ x,
                const float* __restrict__ lstm_wi, const float* __restrict__ lstm_wh,
                const float* __restrict__ lstm_b,
                const float* __restrict__ c0w1, const float* __restrict__ c0w2,
                const float* __restrict__ c0wa, const float* __restrict__ c0wb,
                const float* __restrict__ c0b1, const float* __restrict__ c0b2,
                const float* __restrict__ c0ba, const float* __restrict__ c0bb,
                const float* __restrict__ c1w1, const float* __restrict__ c1w2,
                const float* __restrict__ c1wa, const float* __restrict__ c1wb,
                const float* __restrict__ c1b1, const float* __restrict__ c1b2,
                const float* __restrict__ c1ba, const float* __restrict__ c1bb,
                const float* __restrict__ c2w1, const float* __restrict__ c2w2,
                const float* __restrict__ c2wa, const float* __restrict__ c2wb,
                const float* __restrict__ c2b1, const float* __restrict__ c2b2,
                const float* __restrict__ c2ba, const float* __restrict__ c2bb,
                float* __restrict__ out)
{
    const int bb = blockIdx.x;
    const int t  = threadIdx.x;     // 0..255
    const int k  = t & 3;           // K-chunk slot within the quad
    const int u  = t >> 2;          // unit / row-group index 0..63

    __shared__ __align__(16) float smem[2688];
    float* zL  = smem;
    float* z0  = smem + 96;
    float* z1  = smem + 160;
    float* z2  = smem + 224;
    float* xt0 = smem + 256;
    float* xt1 = smem + 1088;
    float* ot0 = smem + 1920;
    float* ot1 = smem + 2304;

    const long xbase = (long)bb * TSTEPS * INDIM;
    const long obase = (long)bb * TSTEPS * 6;

    // ---- LSTM weights: lane (u,k) holds cols [24k,24k+24) of all 4 gate rows
    auto lwf = [&](int A, int c) -> float {
        int r = A * 64 + u;
        return (c < 13) ? lstm_wi[r * 13 + c]
             : (c < 77) ? lstm_wh[r * 64 + (c - 13)] : 0.f;
    };
#define DEF_WL(A,q) \
    float wl##A##_##q##_0 = lwf(A, 24*k + 4*q + 0); PINF(wl##A##_##q##_0) \
    float wl##A##_##q##_1 = lwf(A, 24*k + 4*q + 1); PINF(wl##A##_##q##_1) \
    float wl##A##_##q##_2 = lwf(A, 24*k + 4*q + 2); PINF(wl##A##_##q##_2) \
    float wl##A##_##q##_3 = lwf(A, 24*k + 4*q + 3); PINF(wl##A##_##q##_3)
    DEF_WL(0,0) DEF_WL(0,1) DEF_WL(0,2) DEF_WL(0,3) DEF_WL(0,4) DEF_WL(0,5)
    DEF_WL(1,0) DEF_WL(1,1) DEF_WL(1,2) DEF_WL(1,3) DEF_WL(1,4) DEF_WL(1,5)
    DEF_WL(2,0) DEF_WL(2,1) DEF_WL(2,2) DEF_WL(2,3) DEF_WL(2,4) DEF_WL(2,5)
    DEF_WL(3,0) DEF_WL(3,1) DEF_WL(3,2) DEF_WL(3,3) DEF_WL(3,4) DEF_WL(3,5)
#undef DEF_WL
    float bL0 = lstm_b[u];        PINF(bL0)
    float bL1 = lstm_b[64 + u];   PINF(bL1)
    float bL2 = lstm_b[128 + u];  PINF(bL2)
    float bL3 = lstm_b[192 + u];  PINF(bL3)

    // ---- CfC weights: quad groups (disjoint lane sets, one name overlay)
    // grp0 (u<35):  row u,    len 48, chunk 12 at 12k (3 float4)
    // grp1 (u<58):  row u-35, len 58, chunk 16 at 16k (4 float4)
    // grp2 (u>=58): row u-58, len 29, chunk 8  at 8k  (2 float4)
    const int grp  = (u < 35) ? 0 : (u < 58) ? 1 : 2;
    const int row  = (grp == 0) ? u : (grp == 1) ? (u - 35) : (u - 58);
    const int rl   = (grp == 0) ? 48 : (grp == 1) ? 58 : 29;
    const int clen = (grp == 0) ? 12 : (grp == 1) ? 16 : 8;
    const int cb   = clen * k;
    const float *W0p, *W1p, *W2p, *W3p;
    float bC0, bC1, bC2, bC3;
    if (grp == 0) {
        W0p = c0w1 + row * 48; W1p = c0w2 + row * 48;
        W2p = c0wa + row * 48; W3p = c0wb + row * 48;
        bC0 = c0b1[row]; bC1 = c0b2[row]; bC2 = c0ba[row]; bC3 = c0bb[row];
    } else if (grp == 1) {
        W0p = c1w1 + row * 58; W1p = c1w2 + row * 58;
        W2p = c1wa + row * 58; W3p = c1wb + row * 58;
        bC0 = c1b1[row]; bC1 = c1b2[row]; bC2 = c1ba[row]; bC3 = c1bb[row];
    } else {
        W0p = c2w1 + row * 29; W1p = c2w2 + row * 29;
        W2p = c2wa + row * 29; W3p = c2wb + row * 29;
        bC0 = c2b1[row]; bC1 = c2b2[row]; bC2 = c2ba[row]; bC3 = c2bb[row];
    }
    PINF(bC0) PINF(bC1) PINF(bC2) PINF(bC3)
    auto cwf = [&](const float* W, int c) -> float {
        int cc = cb + c;
        return (c < clen && cc < rl) ? W[cc] : 0.f;
    };
#define DEF_WC(A,q) \
    float wc##A##_##q##_0 = cwf(W##A##p, 4*q + 0); PINF(wc##A##_##q##_0) \
    float wc##A##_##q##_1 = cwf(W##A##p, 4*q + 1); PINF(wc##A##_##q##_1) \
    float wc##A##_##q##_2 = cwf(W##A##p, 4*q + 2); PINF(wc##A##_##q##_2) \
    float wc##A##_##q##_3 = cwf(W##A##p, 4*q + 3); PINF(wc##A##_##q##_3)
    DEF_WC(0,0) DEF_WC(0,1) DEF_WC(0,2) DEF_WC(0,3)
    DEF_WC(1,0) DEF_WC(1,1) DEF_WC(1,2) DEF_WC(1,3)
    DEF_WC(2,0) DEF_WC(2,1) DEF_WC(2,2) DEF_WC(2,3)
    DEF_WC(3,0) DEF_WC(3,1) DEF_WC(3,2) DEF_WC(3,3)
#undef DEF_WC

    float creg = 0.f;                         // cell state, replicated per quad

    // ---- prologue: zero state, load x tile 0, seed x_0 ----
    smem[t] = 0.f;
    if (t < 208) {                            // 208 float4 = 64 steps x 13
        float4 xi = *(const float4*)(x + xbase + 4 * t);
        *(float4*)&xt0[4 * t] = xi;
    }
    if (t < 13) { float x0 = x[xbase + t]; zL[t] = x0; z0[t] = x0; }
    __syncthreads();

    #pragma unroll 1
    for (int ts = 0; ts < TSTEPS; ++ts) {
        const int par = (ts >> 6) & 1;
        const int lts = ts & 63;

        // ---- phase 1: LSTM (all 256 lanes; K-split-4 by k) ----
        {
            const float4* zc = (const float4*)(zL + 24 * k);
            float4 q0 = zc[0], q1 = zc[1], q2 = zc[2],
                   q3 = zc[3], q4 = zc[4], q5 = zc[5];
            float a0 = 0.f, a1 = 0.f, a2 = 0.f, a3 = 0.f;
            FMA4(a0, wl0, 0, q0) FMA4(a0, wl0, 1, q1) FMA4(a0, wl0, 2, q2)
            FMA4(a0, wl0, 3, q3) FMA4(a0, wl0, 4, q4) FMA4(a0, wl0, 5, q5)
            FMA4(a1, wl1, 0, q0) FMA4(a1, wl1, 1, q1) FMA4(a1, wl1, 2, q2)
            FMA4(a1, wl1, 3, q3) FMA4(a1, wl1, 4, q4) FMA4(a1, wl1, 5, q5)
            FMA4(a2, wl2, 0, q0) FMA4(a2, wl2, 1, q1) FMA4(a2, wl2, 2, q2)
            FMA4(a2, wl2, 3, q3) FMA4(a2, wl2, 4, q4) FMA4(a2, wl2, 5, q5)
            FMA4(a3, wl3, 0, q0) FMA4(a3, wl3, 1, q1) FMA4(a3, wl3, 2, q2)
            FMA4(a3, wl3, 3, q3) FMA4(a3, wl3, 4, q4) FMA4(a3, wl3, 5, q5)
            BFLY4(a0) BFLY4(a1) BFLY4(a2) BFLY4(a3)
            a0 += bL0; a1 += bL1; a2 += bL2; a3 += bL3;   // ia, ig, fg, og
            float cn = creg * fsig(a2 + 1.f) + ftanh(a0) * fsig(a1);
            creg = cn;                      // bit-identical on all 4 quad lanes
            float hl = ftanh(cn) * fsig(a3);
            if (k == 0) {
                if (u < 35)      z0[13 + u] = hl;   // h0
                else if (u < 58) z1[u]      = hl;   // h1 at z1[35..57]
                else             z2[u - 35] = hl;   // h2 at z2[23..28]
            }
        }
        __syncthreads();

        // ---- phase 2: CfC0 (lanes 0..139) || tile refill / out flush ----
        if (grp == 0) {
            const float4* zc = (const float4*)(z0 + 12 * k);
            float4 v0 = zc[0], v1 = zc[1], v2 = zc[2];
            float a0 = 0.f, a1 = 0.f, a2 = 0.f, a3 = 0.f;
            FMA4(a0, wc0, 0, v0) FMA4(a0, wc0, 1, v1) FMA4(a0, wc0, 2, v2)
            FMA4(a1, wc1, 0, v0) FMA4(a1, wc1, 1, v1) FMA4(a1, wc1, 2, v2)
            FMA4(a2, wc2, 0, v0) FMA4(a2, wc2, 1, v1) FMA4(a2, wc2, 2, v2)
            FMA4(a3, wc3, 0, v0) FMA4(a3, wc3, 1, v1) FMA4(a3, wc3, 2, v2)
            BFLY4(a0) BFLY4(a1) BFLY4(a2) BFLY4(a3)
            a0 += bC0; a1 += bC1; a2 += bC2; a3 += bC3;
            float tg = fsig(a2 + a3);
            float f1 = ftanh(a0), f2 = ftanh(a1);
            float o = f1 + tg * (f2 - f1);
            if (k == 0) { z1[row] = o; zL[13 + row] = o; }
        } else {
            if (lts == 62 && (ts + 2) < TSTEPS) {
                // refill x tile [ts+2, ts+66) into buffer par^1 (2 f4/lane)
                int i = (t - 140) * 2;                 // lanes 140..243
                float* dst = par ? xt0 : xt1;
                const float* src = x + xbase + (long)(ts + 2) * 13;
                if (i < 208)     *(float4*)&dst[4*i]     = *(const float4*)(src + 4*i);
                if (i + 1 < 208) *(float4*)&dst[4*(i+1)] = *(const float4*)(src + 4*(i+1));
            }
            if (lts == 0 && ts > 0) {
                // flush out tile for steps [ts-64, ts) from buffer par^1
                int i = t - 140;                       // 0..95 used
                if (i < 96) {
                    const float* src = par ? ot0 : ot1;
                    float4 v = *(const float4*)&src[4 * i];
                    *(float4*)(out + obase + (long)(ts - XT) * 6 + 4 * i) = v;
                }
            }
        }
        __syncthreads();

        // ---- phase 3: CfC1 (lanes 140..231) ----
        if (grp == 1) {
            const float4* zc = (const float4*)(z1 + 16 * k);
            float4 v0 = zc[0], v1 = zc[1], v2 = zc[2], v3 = zc[3];
            float a0 = 0.f, a1 = 0.f, a2 = 0.f, a3 = 0.f;
            FMA4(a0, wc0, 0, v0) FMA4(a0, wc0, 1, v1) FMA4(a0, wc0, 2, v2) FMA4(a0, wc0, 3, v3)
            FMA4(a1, wc1, 0, v0) FMA4(a1, wc1, 1, v1) FMA4(a1, wc1, 2, v2) FMA4(a1, wc1, 3, v3)
            FMA4(a2, wc2, 0, v0) FMA4(a2, wc2, 1, v1) FMA4(a2, wc2, 2, v2) FMA4(a2, wc2, 3, v3)
            FMA4(a3, wc3, 0, v0) FMA4(a3, wc3, 1, v1) FMA4(a3, wc3, 2, v2) FMA4(a3, wc3, 3, v3)
            BFLY4(a0) BFLY4(a1) BFLY4(a2) BFLY4(a3)
            a0 += bC0; a1 += bC1; a2 += bC2; a3 += bC3;
            float tg = fsig(a2 + a3);
            float f1 = ftanh(a0), f2 = ftanh(a1);
            float o = f1 + tg * (f2 - f1);
            if (k == 0) { z2[row] = o; zL[48 + row] = o; }
        }
        __syncthreads();

        // ---- phase 4: CfC2 (lanes 232..255) + x_{t+1} commit from tile ----
        if (grp == 2) {
            const float4* zc = (const float4*)(z2 + 8 * k);
            float4 v0 = zc[0], v1 = zc[1];
            float a0 = 0.f, a1 = 0.f, a2 = 0.f, a3 = 0.f;
            FMA4(a0, wc0, 0, v0) FMA4(a0, wc0, 1, v1)
            FMA4(a1, wc1, 0, v0) FMA4(a1, wc1, 1, v1)
            FMA4(a2, wc2, 0, v0) FMA4(a2, wc2, 1, v1)
            FMA4(a3, wc3, 0, v0) FMA4(a3, wc3, 1, v1)
            BFLY4(a0) BFLY4(a1) BFLY4(a2) BFLY4(a3)
            a0 += bC0; a1 += bC1; a2 += bC2; a3 += bC3;
            float tg = fsig(a2 + a3);
            float f1 = ftanh(a0), f2 = ftanh(a1);
            float o = f1 + tg * (f2 - f1);
            if (k == 0) {
                zL[71 + row] = o;                      // new h[58:64]
                float* ob = par ? ot1 : ot0;           // out tile (LDS only)
                ob[lts * 6 + row] = o;
            }
        } else if (t < 13 && (ts + 1) < TSTEPS) {
            const float* xb = (((ts + 1) >> 6) & 1) ? xt1 : xt0;
            float xn = xb[((ts + 1) & 63) * 13 + t];
            zL[t] = xn; z0[t] = xn;                    // commit x_{t+1}
        }
        __syncthreads();
    }

    // ---- epilogue: flush the last out tile (steps 4032..4095, buffer 1) ----
    if (t < 96) {
        float4 v = *(const float4*)&ot1[4 * t];
        *(float4*)(out + obase + (long)(TSTEPS - XT) * 6 + 4 * t) = v;
    }
}

// ---- head: rewrite pred in place, write unc ----
#define S_GW1 0
#define S_GB1 192
#define S_GW2 224
#define S_GB2 320
#define S_AW1 323
#define S_AB1 515
#define S_AW2 547
#define S_AB2 643
#define S_UW1 646
#define S_UB1 742
#define S_UW2 758
#define S_UB2 854
#define S_TOT 860

__global__ __launch_bounds__(256)
void head_kernel(const float* __restrict__ gw1, const float* __restrict__ gb1,
                 const float* __restrict__ gw2, const float* __restrict__ gb2,
                 const float* __restrict__ aw1, const float* __restrict__ ab1,
                 const float* __restrict__ aw2, const float* __restrict__ ab2,
                 const float* __restrict__ uw1, const float* __restrict__ ub1,
                 const float* __restrict__ uw2, const float* __restrict__ ub2,
                 float* __restrict__ out)
{
    __shared__ float s[S_TOT];
    const int t = threadIdx.x;
    if (t < 192) { s[S_GW1 + t] = gw1[t]; s[S_AW1 + t] = aw1[t]; }
    if (t < 96)  { s[S_GW2 + t] = gw2[t]; s[S_AW2 + t] = aw2[t];
                   s[S_UW1 + t] = uw1[t]; s[S_UW2 + t] = uw2[t]; }
    if (t < 32)  { s[S_GB1 + t] = gb1[t]; s[S_AB1 + t] = ab1[t]; }
    if (t < 16)  { s[S_UB1 + t] = ub1[t]; }
    if (t < 3)   { s[S_GB2 + t] = gb2[t]; s[S_AB2 + t] = ab2[t]; }
    if (t < 6)   { s[S_UB2 + t] = ub2[t]; }
    __syncthreads();

    const long p = (long)blockIdx.x * 256 + t;   // < B*T exactly
    const long base = p * 6;
    float m0 = out[base+0], m1 = out[base+1], m2 = out[base+2];
    float m3 = out[base+3], m4 = out[base+4], m5 = out[base+5];

    float gy0 = s[S_GB2+0], gy1 = s[S_GB2+1], gy2 = s[S_GB2+2];
    float ac0 = s[S_AB2+0], ac1 = s[S_AB2+1], ac2 = s[S_AB2+2];
    #pragma unroll
    for (int i = 0; i < 32; ++i) {
        float hg = s[S_GB1+i] + s[S_GW1+i*6+0]*m0 + s[S_GW1+i*6+1]*m1
                 + s[S_GW1+i*6+2]*m2 + s[S_GW1+i*6+3]*m3
                 + s[S_GW1+i*6+4]*m4 + s[S_GW1+i*6+5]*m5;
        hg = ftanh(hg);
        gy0 += s[S_GW2+i]*hg; gy1 += s[S_GW2+32+i]*hg; gy2 += s[S_GW2+64+i]*hg;
        float ha = s[S_AB1+i] + s[S_AW1+i*6+0]*m0 + s[S_AW1+i*6+1]*m1
                 + s[S_AW1+i*6+2]*m2 + s[S_AW1+i*6+3]*m3
                 + s[S_AW1+i*6+4]*m4 + s[S_AW1+i*6+5]*m5;
        ha = ftanh(ha);
        ac0 += s[S_AW2+i]*ha; ac1 += s[S_AW2+32+i]*ha; ac2 += s[S_AW2+64+i]*ha;
    }
    float u0 = s[S_UB2+0], u1 = s[S_UB2+1], u2 = s[S_UB2+2];
    float u3 = s[S_UB2+3], u4 = s[S_UB2+4], u5 = s[S_UB2+5];
    #pragma unroll
    for (int i = 0; i < 16; ++i) {
        float hu = s[S_UB1+i] + s[S_UW1+i*6+0]*m0 + s[S_UW1+i*6+1]*m1
                 + s[S_UW1+i*6+2]*m2 + s[S_UW1+i*6+3]*m3
                 + s[S_UW1+i*6+4]*m4 + s[S_UW1+i*6+5]*m5;
        hu = fmaxf(hu, 0.f);
        u0 += s[S_UW2+i]*hu;      u1 += s[S_UW2+16+i]*hu; u2 += s[S_UW2+32+i]*hu;
        u3 += s[S_UW2+48+i]*hu;   u4 += s[S_UW2+64+i]*hu; u5 += s[S_UW2+80+i]*hu;
    }
    out[base+0] = gy0; out[base+1] = gy1; out[base+2] = gy2;
    out[base+3] = ac0; out[base+4] = ac1; out[base+5] = ac2;
    const long uoff = (long)BATCH * TSTEPS * 6;
    out[uoff+base+0] = fsoftplus(u0); out[uoff+base+1] = fsoftplus(u1);
    out[uoff+base+2] = fsoftplus(u2); out[uoff+base+3] = fsoftplus(u3);
    out[uoff+base+4] = fsoftplus(u4); out[uoff+base+5] = fsoftplus(u5);
}

extern "C" void kernel_launch(void* const* d_in, const int* in_sizes, int n_in,
                              void* d_out, int out_size, void* d_ws, size_t ws_size,
                              hipStream_t stream) {
    const float* x       = (const float*)d_in[0];
    const float* lstm_wi = (const float*)d_in[1];
    const float* lstm_wh = (const float*)d_in[2];
    const float* lstm_b  = (const float*)d_in[3];
    const float* c0w1 = (const float*)d_in[4];
    const float* c0w2 = (const float*)d_in[5];
    const float* c0wa = (const float*)d_in[6];
    const float* c0wb = (const float*)d_in[7];
    const float* c0b1 = (const float*)d_in[8];
    const float* c0b2 = (const float*)d_in[9];
    const float* c0ba = (const float*)d_in[10];
    const float* c0bb = (const float*)d_in[11];
    const float* c1w1 = (const float*)d_in[12];
    const float* c1w2 = (const float*)d_in[13];
    const float* c1wa = (const float*)d_in[14];
    const float* c1wb = (const float*)d_in[15];
    const float* c1b1 = (const float*)d_in[16];
    const float* c1b2 = (const float*)d_in[17];
    const float* c1ba = (const float*)d_in[18];
    const float* c1bb = (const float*)d_in[19];
    const float* c2w1 = (const float*)d_in[20];
    const float* c2w2 = (const float*)d_in[21];
    const float* c2wa = (const float*)d_in[22];
    const float* c2wb = (const float*)d_in[23];
    const float* c2b1 = (const float*)d_in[24];
    const float* c2b2 = (const float*)d_in[25];
    const float* c2ba = (const float*)d_in[26];
    const float* c2bb = (const float*)d_in[27];
    const float* gw1 = (const float*)d_in[28];
    const float* gb1 = (const float*)d_in[29];
    const float* gw2 = (const float*)d_in[30];
    const float* gb2 = (const float*)d_in[31];
    const float* aw1 = (const float*)d_in[32];
    const float* ab1 = (const float*)d_in[33];
    const float* aw2 = (const float*)d_in[34];
    const float* ab2 = (const float*)d_in[35];
    const float* uw1 = (const float*)d_in[36];
    const float* ub1 = (const float*)d_in[37];
    const float* uw2 = (const float*)d_in[38];
    const float* ub2 = (const float*)d_in[39];
    float* out = (float*)d_out;

    rnn_kernel<<<BATCH, 256, 0, stream>>>(x, lstm_wi, lstm_wh, lstm_b,
        c0w1, c0w2, c0wa, c0wb, c0b1, c0b2, c0ba, c0bb,
        c1w1, c1w2, c1wa, c1wb, c1b1, c1b2, c1ba, c1bb,
        c2w1, c2w2, c2wa, c2wb, c2b1, c2b2, c2ba, c2bb, out);

    head_kernel<<<(BATCH * TSTEPS) / 256, 256, 0, stream>>>(
        gw1, gb1, gw2, gb2, aw1, ab1, aw2, ab2, uw1, ub1, uw2, ub2, out);
}